// Round 10
// baseline (138.587 us; speedup 1.0000x reference)
//
#include <hip/hip_runtime.h>
#include <cfloat>

typedef __bf16 bf16x8 __attribute__((ext_vector_type(8)));
typedef float f32x16 __attribute__((ext_vector_type(16)));

namespace {
constexpr int kHW = 4096;     // 64*64 spatial per image
constexpr int kC = 64;        // channels == code dim
constexpr float kInvN = 1.0f / 65536.0f;

// ws layout (bytes): [0, 294912): A-frags (32 chunks * 9 slots * 64 lanes * 16B)
//   [294912, +4096): hist   [299008, +16): lossacc   [299024, +262144): idx
// Frag slot order per chunk: 0..3 = Ah(ks), 4..7 = Al(ks), 8 = bias.

// ---------------- prep: build -2*C bf16-split fragments + bias frag ---------
__global__ __launch_bounds__(256) void prep_kernel(
    const float* __restrict__ cb, uint4* __restrict__ frags,
    unsigned int* __restrict__ hist, float* __restrict__ lossacc) {
  const int c = blockIdx.x;        // chunk of 32 codes
  const int t = threadIdx.x;
  const int lane = t & 63, wv = t >> 6;
  const int lo = lane & 31, hi = lane >> 5;
  const int code = c * 32 + lo;
  const int ks = wv;

  const float* row = cb + code * kC + ks * 16 + hi * 8;
  float4 v0 = *reinterpret_cast<const float4*>(row);
  float4 v1 = *reinterpret_cast<const float4*>(row + 4);
  float vv[8] = {v0.x, v0.y, v0.z, v0.w, v1.x, v1.y, v1.z, v1.w};
  bf16x8 fh, fl;
  #pragma unroll
  for (int e = 0; e < 8; ++e) {
    float v = -2.0f * vv[e];
    __bf16 h = (__bf16)v;
    fh[e] = h;
    fl[e] = (__bf16)(v - (float)h);
  }
  frags[(c * 9 + ks) * 64 + lane] = *reinterpret_cast<uint4*>(&fh);
  frags[(c * 9 + 4 + ks) * 64 + lane] = *reinterpret_cast<uint4*>(&fl);

  if (wv == 0) {
    bf16x8 fb;
    #pragma unroll
    for (int e = 0; e < 8; ++e) fb[e] = (__bf16)0.0f;
    if (hi == 0) {
      float s = 0.0f;
      #pragma unroll
      for (int d = 0; d < kC; d += 4) {
        float4 v = *reinterpret_cast<const float4*>(cb + code * kC + d);
        s = fmaf(v.x, v.x, fmaf(v.y, v.y, fmaf(v.z, v.z, fmaf(v.w, v.w, s))));
      }
      __bf16 h = (__bf16)s;
      fb[0] = h;
      fb[1] = (__bf16)(s - (float)h);
    }
    frags[(c * 9 + 8) * 64 + lane] = *reinterpret_cast<uint4*>(&fb);
  }
  if (t < 32) hist[c * 32 + t] = 0u;
  if (c == 0 && t == 0) lossacc[0] = 0.0f;
}

// ---------------- argmin GEMM (R8 geometry, compiler-pipelined) -------------
// Block = 4 waves, 64 sites. Wave wv: site-group (wv&1), K-half (wv>>1).
// X tile staged once in LDS (coalesced float4); chunk loop FULLY UNROLLED,
// no manual prefetch — compiler software-pipelines loads across chunks.
__global__ __launch_bounds__(256) void vq_argmin_kernel(
    const float* __restrict__ in, const bf16x8* __restrict__ frags,
    unsigned int* __restrict__ hist, unsigned int* __restrict__ idxOut) {
  __shared__ __align__(16) float sX[64][64];   // [d][site] 16KB
  __shared__ float sVal[4][32];
  __shared__ int sIdxW[4][32];
  const int t = threadIdx.x;
  const int lane = t & 63, wv = t >> 6;
  const int lo = lane & 31, hi = lane >> 5;
  const int g = wv & 1, h = wv >> 1;          // site-group, K-half
  const int siteBase = blockIdx.x * 64;
  const int b = siteBase >> 12, hw0 = siteBase & 4095;
  const float* xin = in + b * (kC * kHW) + hw0;

  // --- stage X tile [64 d][64 s]: coalesced float4 along s ---
  {
    const int s4 = (t & 15) * 4;
    const int d0 = t >> 4;                    // 0..15
    #pragma unroll
    for (int i = 0; i < 4; ++i) {
      const int d = d0 + i * 16;
      *reinterpret_cast<float4*>(&sX[d][s4]) =
          *reinterpret_cast<const float4*>(xin + d * kHW + s4);
    }
  }
  __syncthreads();

  // --- X fragments from LDS column (conflict-free: bank == lo) ---
  bf16x8 Bh[4], Bl[4];
  const int col = g * 32 + lo;
  #pragma unroll
  for (int ks = 0; ks < 4; ++ks) {
    #pragma unroll
    for (int e = 0; e < 8; ++e) {
      const int d = ks * 16 + hi * 8 + e;
      float v = sX[d][col];
      __bf16 hh = (__bf16)v;
      Bh[ks][e] = hh;
      Bl[ks][e] = (__bf16)(v - (float)hh);
    }
  }
  bf16x8 ones;
  #pragma unroll
  for (int e = 0; e < 8; ++e) ones[e] = (__bf16)0.0f;
  if (hi == 0) { ones[0] = (__bf16)1.0f; ones[1] = (__bf16)1.0f; }
  f32x16 zero;
  #pragma unroll
  for (int r = 0; r < 16; ++r) zero[r] = 0.0f;

  float best[16];
  int bch[16];
  #pragma unroll
  for (int r = 0; r < 16; ++r) { best[r] = FLT_MAX; bch[r] = 0; }

  const bf16x8* fA = frags + lane;   // entry j of chunk c at fA[(c*9+j)*64]
  const int c0 = h * 16;

  #pragma unroll                     // FULL unroll: compiler pipelines loads
  for (int cc = 0; cc < 16; ++cc) {
    const int c = c0 + cc;
    bf16x8 F[9];
    #pragma unroll
    for (int j = 0; j < 9; ++j) F[j] = fA[(c * 9 + j) * 64];
    // dist = bias + (-2c).x via 3-pass bf16 split
    f32x16 a = __builtin_amdgcn_mfma_f32_32x32x16_bf16(F[8], ones, zero, 0, 0, 0);
    #pragma unroll
    for (int ks = 0; ks < 4; ++ks)
      a = __builtin_amdgcn_mfma_f32_32x32x16_bf16(F[ks], Bh[ks], a, 0, 0, 0);
    #pragma unroll
    for (int ks = 0; ks < 4; ++ks)
      a = __builtin_amdgcn_mfma_f32_32x32x16_bf16(F[4 + ks], Bh[ks], a, 0, 0, 0);
    #pragma unroll
    for (int ks = 0; ks < 4; ++ks)
      a = __builtin_amdgcn_mfma_f32_32x32x16_bf16(F[ks], Bl[ks], a, 0, 0, 0);
    #pragma unroll
    for (int r = 0; r < 16; ++r) {
      bool p = a[r] < best[r];         // strict < : earliest chunk wins ties
      best[r] = p ? a[r] : best[r];
      bch[r] = p ? c : bch[r];
    }
  }

  // --- per-lane (val, idx) reduce over 16 acc rows, then half-merge ---
  float bv = best[0];
  int bidx = bch[0] * 32 + (hi << 2);       // kloc(r=0) = 0 + 4*hi
  #pragma unroll
  for (int r = 1; r < 16; ++r) {
    const int kloc = (r & 3) + 8 * (r >> 2) + (hi << 2);
    int idx = bch[r] * 32 + kloc;
    float v = best[r];
    if (v < bv || (v == bv && idx < bidx)) { bv = v; bidx = idx; }
  }
  float ov = __shfl_xor(bv, 32, 64);
  int oi = __shfl_xor(bidx, 32, 64);
  if (ov < bv || (ov == bv && oi < bidx)) { bv = ov; bidx = oi; }
  if (hi == 0) {
    sVal[wv][lo] = bv;
    sIdxW[wv][lo] = bidx;
  }
  __syncthreads();
  // waves 0,1 (K-half 0) merge with partner wave (wv+2, K-half 1)
  if (wv < 2 && hi == 0) {
    float v2 = sVal[wv + 2][lo];
    int i2 = sIdxW[wv + 2][lo];
    if (v2 < bv || (v2 == bv && i2 < bidx)) { bv = v2; bidx = i2; }
    idxOut[siteBase + g * 32 + lo] = (unsigned int)bidx;
    atomicAdd(&hist[bidx], 1u);
  }
}

// ---------------- epilogue: gather + ST output + loss -----------------------
// 256 blocks x 256 thr. Block owns 256 sites. Thread: 4 consecutive sites
// (float4 x-loads) x 16 dims. Loss block-reduced -> one atomic per block.
__global__ __launch_bounds__(256) void epilogue_kernel(
    const float* __restrict__ in, const float* __restrict__ cb,
    const unsigned int* __restrict__ idx, float* __restrict__ lossacc,
    float* __restrict__ qout) {
  __shared__ float sRed[4];
  const int t = threadIdx.x;
  const int sg = t & 63, dg = t >> 6;
  const int siteBase = blockIdx.x * 256 + sg * 4;
  const int b = siteBase >> 12, hw = siteBase & 4095;
  const float* xb = in + b * (kC * kHW) + hw;
  float* ob = qout + b * (kC * kHW) + hw;
  uint4 cc = *reinterpret_cast<const uint4*>(idx + siteBase);
  const float* q0 = cb + cc.x * kC;
  const float* q1 = cb + cc.y * kC;
  const float* q2 = cb + cc.z * kC;
  const float* q3 = cb + cc.w * kC;
  float ls = 0.0f;
  #pragma unroll
  for (int j = 0; j < 16; ++j) {
    const int d = dg * 16 + j;
    float4 xv = *reinterpret_cast<const float4*>(xb + d * kHW);
    float d0 = q0[d] - xv.x;   // q - x
    float d1 = q1[d] - xv.y;
    float d2 = q2[d] - xv.z;
    float d3 = q3[d] - xv.w;
    ls = fmaf(d0, d0, ls);
    ls = fmaf(d1, d1, ls);
    ls = fmaf(d2, d2, ls);
    ls = fmaf(d3, d3, ls);
    float* o = ob + d * kHW;               // qout = d_out+1 (4B-misaligned for
    o[0] = xv.x + d0;                      // float4) -> scalar stores, still
    o[1] = xv.y + d1;                      // coalesced per wave
    o[2] = xv.z + d2;
    o[3] = xv.w + d3;
  }
  #pragma unroll
  for (int off = 32; off; off >>= 1) ls += __shfl_xor(ls, off, 64);
  if ((t & 63) == 0) sRed[t >> 6] = ls;
  __syncthreads();
  if (t == 0) {
    float s = (sRed[0] + sRed[1]) + (sRed[2] + sRed[3]);
    atomicAdd(lossacc, s);
  }
}

// ---------------- finalize: loss scalar + perplexity ------------------------
__global__ __launch_bounds__(1024) void finalize_kernel(
    const unsigned int* __restrict__ hist, const float* __restrict__ lossacc,
    const float* __restrict__ beta, float* __restrict__ out) {
  __shared__ float red[16];
  const int t = threadIdx.x;
  float e = (float)hist[t] * kInvN;
  float term = e * logf(e + 1e-10f);
  #pragma unroll
  for (int off = 32; off; off >>= 1) term += __shfl_xor(term, off, 64);
  if ((t & 63) == 0) red[t >> 6] = term;
  __syncthreads();
  if (t == 0) {
    float h = 0.0f;
    #pragma unroll
    for (int i = 0; i < 16; ++i) h += red[i];
    out[1 + 4194304] = expf(-h);                                  // perplexity
    out[0] = lossacc[0] * (1.0f + beta[0]) * 10.0f / 4194304.0f;  // loss
  }
}
}  // namespace

extern "C" void kernel_launch(void* const* d_in, const int* in_sizes, int n_in,
                              void* d_out, int out_size, void* d_ws, size_t ws_size,
                              hipStream_t stream) {
  const float* inputs = (const float*)d_in[0];   // [16,64,64,64] fp32
  const float* cb = (const float*)d_in[1];       // [1024,64] fp32
  const float* beta = (const float*)d_in[2];     // scalar
  float* out = (float*)d_out;                    // [1 + 4194304 + 1]

  uint4* frags = (uint4*)d_ws;                                        // 294912 B
  unsigned int* hist = (unsigned int*)((char*)d_ws + 294912);         // 4 KB
  float* lossacc = (float*)((char*)d_ws + 299008);                    // 16 B
  unsigned int* idx = (unsigned int*)((char*)d_ws + 299024);          // 256 KB

  prep_kernel<<<32, 256, 0, stream>>>(cb, frags, hist, lossacc);
  vq_argmin_kernel<<<1024, 256, 0, stream>>>(inputs, (const bf16x8*)frags,
                                             hist, idx);
  epilogue_kernel<<<256, 256, 0, stream>>>(inputs, cb, idx, lossacc, out + 1);
  finalize_kernel<<<1, 1024, 0, stream>>>(hist, lossacc, beta, out);
}

// Round 11
// 124.597 us; speedup vs baseline: 1.1123x; 1.1123x over previous
//
#include <hip/hip_runtime.h>
#include <cfloat>

typedef __bf16 bf16x8 __attribute__((ext_vector_type(8)));
typedef float f32x16 __attribute__((ext_vector_type(16)));

namespace {
constexpr int kHW = 4096;     // 64*64 spatial per image
constexpr int kC = 64;        // channels == code dim
constexpr float kInvN = 1.0f / 65536.0f;
constexpr int kChunkBytes = 9216;          // 9 frags * 64 lanes * 16B
constexpr int kHalfBytes = 16 * kChunkBytes;   // 147456 B = one K-half

// ws layout (bytes): [0, 294912): A-frags (32 chunks * 9 slots * 64 lanes * 16B)
//   [294912, +4096): hist   [299008, +16): lossacc   [299024, +262144): idx
// Frag slot order per chunk: 0..3 = Ah(ks), 4..7 = Al(ks), 8 = bias.

// ---------------- prep: build -2*C bf16-split fragments + bias frag ---------
__global__ __launch_bounds__(256) void prep_kernel(
    const float* __restrict__ cb, uint4* __restrict__ frags,
    unsigned int* __restrict__ hist, float* __restrict__ lossacc) {
  const int c = blockIdx.x;        // chunk of 32 codes
  const int t = threadIdx.x;
  const int lane = t & 63, wv = t >> 6;
  const int lo = lane & 31, hi = lane >> 5;
  const int code = c * 32 + lo;
  const int ks = wv;

  const float* row = cb + code * kC + ks * 16 + hi * 8;
  float4 v0 = *reinterpret_cast<const float4*>(row);
  float4 v1 = *reinterpret_cast<const float4*>(row + 4);
  float vv[8] = {v0.x, v0.y, v0.z, v0.w, v1.x, v1.y, v1.z, v1.w};
  bf16x8 fh, fl;
  #pragma unroll
  for (int e = 0; e < 8; ++e) {
    float v = -2.0f * vv[e];
    __bf16 h = (__bf16)v;
    fh[e] = h;
    fl[e] = (__bf16)(v - (float)h);
  }
  frags[(c * 9 + ks) * 64 + lane] = *reinterpret_cast<uint4*>(&fh);
  frags[(c * 9 + 4 + ks) * 64 + lane] = *reinterpret_cast<uint4*>(&fl);

  if (wv == 0) {
    bf16x8 fb;
    #pragma unroll
    for (int e = 0; e < 8; ++e) fb[e] = (__bf16)0.0f;
    if (hi == 0) {
      float s = 0.0f;
      #pragma unroll
      for (int d = 0; d < kC; d += 4) {
        float4 v = *reinterpret_cast<const float4*>(cb + code * kC + d);
        s = fmaf(v.x, v.x, fmaf(v.y, v.y, fmaf(v.z, v.z, fmaf(v.w, v.w, s))));
      }
      __bf16 h = (__bf16)s;
      fb[0] = h;
      fb[1] = (__bf16)(s - (float)h);
    }
    frags[(c * 9 + 8) * 64 + lane] = *reinterpret_cast<uint4*>(&fb);
  }
  if (t < 32) hist[c * 32 + t] = 0u;
  if (c == 0 && t == 0) lossacc[0] = 0.0f;
}

// ---------------- argmin GEMM: LDS-resident K-half, barrier-free loop -------
// 256 blocks x 512 thr (8 waves x 32 sites). Stage a full K-half (16 chunks,
// 144KB) into LDS once; hot loop = ds_read_b128 + MFMA + select, NO barriers,
// NO global loads, NO vmcnt. Restage once for the second half. Each wave owns
// its 32 sites for all 1024 codes -> no cross-wave merge.
__global__ __launch_bounds__(512) void vq_argmin_kernel(
    const float* __restrict__ in, const char* __restrict__ fragsB,
    unsigned int* __restrict__ hist, unsigned int* __restrict__ idxOut) {
  __shared__ __align__(16) char sF[kHalfBytes];   // 147456 B of 160K
  const int t = threadIdx.x;
  const int lane = t & 63, wv = t >> 6;           // 8 waves
  const int lo = lane & 31, hi = lane >> 5;
  const int site = blockIdx.x * 256 + wv * 32 + lo;
  const int b = site >> 12, hw = site & 4095;
  const float* xp = in + b * (kC * kHW) + hw;

  // stage one K-half (16 chunks) into LDS: 18 rounds x 8KB (8 waves x 1KB)
  auto stage = [&](int h) {
    const char* g = fragsB + h * kHalfBytes;
    #pragma unroll
    for (int r = 0; r < 18; ++r) {
      const int off = r * 8192 + wv * 1024 + lane * 16;
      __builtin_amdgcn_global_load_lds((const uint32_t*)(g + off),
                                       (uint32_t*)(sF + off), 16, 0, 0);
    }
  };

  stage(0);   // in flight while we build X fragments

  // --- X fragments: bf16 hi/lo split, 8 consecutive d per lane-half ---
  bf16x8 Bh[4], Bl[4];
  #pragma unroll
  for (int ks = 0; ks < 4; ++ks) {
    #pragma unroll
    for (int e = 0; e < 8; ++e) {
      const int d = ks * 16 + hi * 8 + e;
      float v = xp[d * kHW];
      __bf16 hh = (__bf16)v;
      Bh[ks][e] = hh;
      Bl[ks][e] = (__bf16)(v - (float)hh);
    }
  }
  bf16x8 ones;
  #pragma unroll
  for (int e = 0; e < 8; ++e) ones[e] = (__bf16)0.0f;
  if (hi == 0) { ones[0] = (__bf16)1.0f; ones[1] = (__bf16)1.0f; }
  f32x16 zero;
  #pragma unroll
  for (int r = 0; r < 16; ++r) zero[r] = 0.0f;

  float best[16];
  int bch[16];
  #pragma unroll
  for (int r = 0; r < 16; ++r) { best[r] = FLT_MAX; bch[r] = 0; }

  // scan the staged 16 chunks; gbase = global chunk id of chunk 0
  auto scanHalf = [&](int gbase) {
    #pragma unroll 2
    for (int c = 0; c < 16; ++c) {
      const char* lb = sF + c * kChunkBytes + lane * 16;
      bf16x8 F[9];
      #pragma unroll
      for (int j = 0; j < 9; ++j)
        F[j] = *reinterpret_cast<const bf16x8*>(lb + j * 1024);
      // dist = bias + (-2c).x via 3-pass bf16 split; two chains (5 & 8 deep)
      f32x16 a1 = __builtin_amdgcn_mfma_f32_32x32x16_bf16(F[8], ones, zero, 0, 0, 0);
      f32x16 a2 = zero;
      #pragma unroll
      for (int ks = 0; ks < 4; ++ks)
        a1 = __builtin_amdgcn_mfma_f32_32x32x16_bf16(F[ks], Bh[ks], a1, 0, 0, 0);
      #pragma unroll
      for (int ks = 0; ks < 4; ++ks)
        a2 = __builtin_amdgcn_mfma_f32_32x32x16_bf16(F[4 + ks], Bh[ks], a2, 0, 0, 0);
      #pragma unroll
      for (int ks = 0; ks < 4; ++ks)
        a2 = __builtin_amdgcn_mfma_f32_32x32x16_bf16(F[ks], Bl[ks], a2, 0, 0, 0);
      const int gc = gbase + c;
      #pragma unroll
      for (int r = 0; r < 16; ++r) {
        float d = a1[r] + a2[r];
        bool p = d < best[r];            // strict < : earliest chunk wins ties
        best[r] = p ? d : best[r];
        bch[r] = p ? gc : bch[r];
      }
    }
  };

  asm volatile("s_waitcnt vmcnt(0)" ::: "memory");
  __syncthreads();
  scanHalf(0);

  __syncthreads();                       // all waves done reading half 0
  stage(1);
  asm volatile("s_waitcnt vmcnt(0)" ::: "memory");
  __syncthreads();
  scanHalf(16);

  // --- per-lane (val, idx) reduce over 16 acc rows, then xor-32 merge ---
  float bv = best[0];
  int bidx = bch[0] * 32 + (hi << 2);        // kloc(r=0) = 0 + 4*hi
  #pragma unroll
  for (int r = 1; r < 16; ++r) {
    const int kloc = (r & 3) + 8 * (r >> 2) + (hi << 2);
    int idx = bch[r] * 32 + kloc;
    float v = best[r];
    if (v < bv || (v == bv && idx < bidx)) { bv = v; bidx = idx; }
  }
  float ov = __shfl_xor(bv, 32, 64);
  int oi = __shfl_xor(bidx, 32, 64);
  if (ov < bv || (ov == bv && oi < bidx)) { bv = ov; bidx = oi; }
  if (hi == 0) {
    idxOut[site] = (unsigned int)bidx;
    atomicAdd(&hist[bidx], 1u);
  }
}

// ---------------- epilogue: gather + ST output + loss -----------------------
// 256 blocks x 256 thr. Block owns 256 sites. Thread: 4 consecutive sites
// (float4 x-loads) x 16 dims. Loss block-reduced -> one atomic per block.
__global__ __launch_bounds__(256) void epilogue_kernel(
    const float* __restrict__ in, const float* __restrict__ cb,
    const unsigned int* __restrict__ idx, float* __restrict__ lossacc,
    float* __restrict__ qout) {
  __shared__ float sRed[4];
  const int t = threadIdx.x;
  const int sg = t & 63, dg = t >> 6;
  const int siteBase = blockIdx.x * 256 + sg * 4;
  const int b = siteBase >> 12, hw = siteBase & 4095;
  const float* xb = in + b * (kC * kHW) + hw;
  float* ob = qout + b * (kC * kHW) + hw;
  uint4 cc = *reinterpret_cast<const uint4*>(idx + siteBase);
  const float* q0 = cb + cc.x * kC;
  const float* q1 = cb + cc.y * kC;
  const float* q2 = cb + cc.z * kC;
  const float* q3 = cb + cc.w * kC;
  float ls = 0.0f;
  #pragma unroll
  for (int j = 0; j < 16; ++j) {
    const int d = dg * 16 + j;
    float4 xv = *reinterpret_cast<const float4*>(xb + d * kHW);
    float d0 = q0[d] - xv.x;   // q - x
    float d1 = q1[d] - xv.y;
    float d2 = q2[d] - xv.z;
    float d3 = q3[d] - xv.w;
    ls = fmaf(d0, d0, ls);
    ls = fmaf(d1, d1, ls);
    ls = fmaf(d2, d2, ls);
    ls = fmaf(d3, d3, ls);
    float* o = ob + d * kHW;               // qout = d_out+1 (4B-misaligned for
    o[0] = xv.x + d0;                      // float4) -> scalar stores, still
    o[1] = xv.y + d1;                      // coalesced per wave
    o[2] = xv.z + d2;
    o[3] = xv.w + d3;
  }
  #pragma unroll
  for (int off = 32; off; off >>= 1) ls += __shfl_xor(ls, off, 64);
  if ((t & 63) == 0) sRed[t >> 6] = ls;
  __syncthreads();
  if (t == 0) {
    float s = (sRed[0] + sRed[1]) + (sRed[2] + sRed[3]);
    atomicAdd(lossacc, s);
  }
}

// ---------------- finalize: loss scalar + perplexity ------------------------
__global__ __launch_bounds__(1024) void finalize_kernel(
    const unsigned int* __restrict__ hist, const float* __restrict__ lossacc,
    const float* __restrict__ beta, float* __restrict__ out) {
  __shared__ float red[16];
  const int t = threadIdx.x;
  float e = (float)hist[t] * kInvN;
  float term = e * logf(e + 1e-10f);
  #pragma unroll
  for (int off = 32; off; off >>= 1) term += __shfl_xor(term, off, 64);
  if ((t & 63) == 0) red[t >> 6] = term;
  __syncthreads();
  if (t == 0) {
    float h = 0.0f;
    #pragma unroll
    for (int i = 0; i < 16; ++i) h += red[i];
    out[1 + 4194304] = expf(-h);                                  // perplexity
    out[0] = lossacc[0] * (1.0f + beta[0]) * 10.0f / 4194304.0f;  // loss
  }
}
}  // namespace

extern "C" void kernel_launch(void* const* d_in, const int* in_sizes, int n_in,
                              void* d_out, int out_size, void* d_ws, size_t ws_size,
                              hipStream_t stream) {
  const float* inputs = (const float*)d_in[0];   // [16,64,64,64] fp32
  const float* cb = (const float*)d_in[1];       // [1024,64] fp32
  const float* beta = (const float*)d_in[2];     // scalar
  float* out = (float*)d_out;                    // [1 + 4194304 + 1]

  uint4* frags = (uint4*)d_ws;                                        // 294912 B
  unsigned int* hist = (unsigned int*)((char*)d_ws + 294912);         // 4 KB
  float* lossacc = (float*)((char*)d_ws + 299008);                    // 16 B
  unsigned int* idx = (unsigned int*)((char*)d_ws + 299024);          // 256 KB

  prep_kernel<<<32, 256, 0, stream>>>(cb, frags, hist, lossacc);
  vq_argmin_kernel<<<256, 512, 0, stream>>>(inputs, (const char*)d_ws,
                                            hist, idx);
  epilogue_kernel<<<256, 256, 0, stream>>>(inputs, cb, idx, lossacc, out + 1);
  finalize_kernel<<<1, 1024, 0, stream>>>(hist, lossacc, beta, out);
}